// Round 1
// baseline (1480.990 us; speedup 1.0000x reference)
//
#include <hip/hip_runtime.h>
#include <hip/hip_bf16.h>

#define NN 100000
#define NE 1600000
#define DD 64
#define HID 128

// ---------------------------------------------------------------------------
// Edge kernel: one wave per edge.
//   proj_j = lin_b[j] + sum_k edge_attr[e][k] * lin_w[j][k]
//   msg_j  = relu(x[src][j] + proj_j)
//   atomicAdd(agg[dst][j], msg_j)     (agg pre-initialized to x => h = x+agg)
// lin_w row j lives in 64 VGPRs of lane j; edge_attr row is wave-uniform ->
// scalar loads, FMAs take the broadcast from SGPRs.
// ---------------------------------------------------------------------------
__global__ __launch_bounds__(256, 4)
void edge_kernel(const float* __restrict__ edge_attr,
                 const int*   __restrict__ edge_index,
                 const float* __restrict__ x,
                 const float* __restrict__ lin_w,
                 const float* __restrict__ lin_b,
                 float* agg)
{
    const int lane = threadIdx.x & 63;
    int wid = blockIdx.x * (blockDim.x >> 6) + (threadIdx.x >> 6);
    wid = __builtin_amdgcn_readfirstlane(wid);
    const int nwaves = gridDim.x * (blockDim.x >> 6);

    // Load lin_w row `lane` into registers (64 VGPRs).
    float w[DD];
    const float4* wrow = reinterpret_cast<const float4*>(lin_w + lane * DD);
    #pragma unroll
    for (int q = 0; q < DD / 4; ++q) {
        float4 v = wrow[q];
        w[4 * q + 0] = v.x; w[4 * q + 1] = v.y;
        w[4 * q + 2] = v.z; w[4 * q + 3] = v.w;
    }
    const float bj = lin_b[lane];

    for (int e = wid; e < NE; e += nwaves) {
        const int src = edge_index[e];        // wave-uniform -> s_load
        const int dst = edge_index[NE + e];   // wave-uniform -> s_load
        const float* ea = edge_attr + (size_t)e * DD;  // uniform base

        float acc = bj;
        #pragma unroll
        for (int k = 0; k < DD; ++k)
            acc = fmaf(ea[k], w[k], acc);     // s_load broadcast * VGPR

        float xv = x[(size_t)src * DD + lane]; // coalesced 256B gather
        float m = xv + acc;
        m = m > 0.0f ? m : 0.0f;
        unsafeAtomicAdd(&agg[(size_t)dst * DD + lane], m);
    }
}

// ---------------------------------------------------------------------------
// Node MLP: one wave per PAIR of nodes.
//   h1 = relu(W0 h + b0)   layer1: lane j computes rows j and j+64, h from
//                          wave-uniform scalar loads, W0 rows in 128 VGPRs.
//   out = W1 h1 + b1       layer2: W1 transposed in LDS (lane-consecutive,
//                          conflict-free); h1 broadcast from per-wave LDS;
//                          W1t reads amortized over the 2 nodes.
// ---------------------------------------------------------------------------
__global__ __launch_bounds__(256, 2)
void mlp_kernel(const float* __restrict__ h_in,
                float* out,
                const float* __restrict__ w0, const float* __restrict__ b0,
                const float* __restrict__ w1, const float* __restrict__ b1)
{
    __shared__ float W1t[HID * DD];          // W1t[k*64 + j] = w1[j*128 + k]
    __shared__ float h1buf[4][2][HID];       // [wave][node-in-pair][k]

    for (int i = threadIdx.x; i < HID * DD; i += blockDim.x) {
        int j = i >> 7;          // w1 row (output dim, 0..63)
        int k = i & 127;         // w1 col (hidden dim, 0..127)
        W1t[k * DD + j] = w1[i]; // coalesced global read
    }
    __syncthreads();

    const int lane = threadIdx.x & 63;
    const int wv   = threadIdx.x >> 6;
    int wid = blockIdx.x * (blockDim.x >> 6) + wv;
    wid = __builtin_amdgcn_readfirstlane(wid);
    const int nwaves = gridDim.x * (blockDim.x >> 6);

    // W0 rows `lane` and `lane+64` in registers (128 VGPRs).
    float w0a[DD], w0b[DD];
    const float4* r0 = reinterpret_cast<const float4*>(w0 + lane * DD);
    const float4* r1 = reinterpret_cast<const float4*>(w0 + (lane + 64) * DD);
    #pragma unroll
    for (int q = 0; q < DD / 4; ++q) {
        float4 va = r0[q], vb = r1[q];
        w0a[4*q+0]=va.x; w0a[4*q+1]=va.y; w0a[4*q+2]=va.z; w0a[4*q+3]=va.w;
        w0b[4*q+0]=vb.x; w0b[4*q+1]=vb.y; w0b[4*q+2]=vb.z; w0b[4*q+3]=vb.w;
    }
    const float b0a = b0[lane], b0b = b0[lane + 64];
    const float b1j = b1[lane];

    const int npairs = NN / 2;
    for (int p = wid; p < npairs; p += nwaves) {
        // ---- layer 1, two nodes sequentially (SGPR h reused) ----
        #pragma unroll
        for (int t = 0; t < 2; ++t) {
            const float* h = h_in + (size_t)(2 * p + t) * DD;  // uniform
            float a0 = b0a, a1 = b0b;
            #pragma unroll
            for (int k = 0; k < DD; ++k) {
                float hk = h[k];                 // s_load broadcast
                a0 = fmaf(hk, w0a[k], a0);
                a1 = fmaf(hk, w0b[k], a1);
            }
            a0 = a0 > 0.0f ? a0 : 0.0f;
            a1 = a1 > 0.0f ? a1 : 0.0f;
            h1buf[wv][t][lane]      = a0;
            h1buf[wv][t][lane + 64] = a1;
        }
        // wave-synchronous LDS (same wave wrote it; compiler inserts waitcnt)

        // ---- layer 2, both nodes share the W1t reads ----
        float acc0 = b1j, acc1 = b1j;
        #pragma unroll
        for (int k = 0; k < HID; ++k) {
            float wk = W1t[k * DD + lane];       // conflict-free ds_read
            acc0 = fmaf(h1buf[wv][0][k], wk, acc0);
            acc1 = fmaf(h1buf[wv][1][k], wk, acc1);
        }
        out[(size_t)(2 * p + 0) * DD + lane] = acc0;
        out[(size_t)(2 * p + 1) * DD + lane] = acc1;
    }
}

extern "C" void kernel_launch(void* const* d_in, const int* in_sizes, int n_in,
                              void* d_out, int out_size, void* d_ws, size_t ws_size,
                              hipStream_t stream) {
    const float* x         = (const float*)d_in[0];
    const int*   edge_index= (const int*)  d_in[1];
    const float* edge_attr = (const float*)d_in[2];
    const float* lin_w     = (const float*)d_in[3];
    const float* lin_b     = (const float*)d_in[4];
    const float* w0        = (const float*)d_in[5];
    const float* b0        = (const float*)d_in[6];
    const float* w1        = (const float*)d_in[7];
    const float* b1        = (const float*)d_in[8];
    float* out = (float*)d_out;

    const size_t hbytes = (size_t)NN * DD * sizeof(float);
    // Aggregation buffer = h buffer. Prefer workspace; fall back to in-place
    // in d_out (each MLP wave reads exactly the rows it later writes).
    float* hbuf = (ws_size >= hbytes) ? (float*)d_ws : out;

    // h starts as x (EPS=0: h = (1+eps)*x + agg).
    hipMemcpyAsync(hbuf, x, hbytes, hipMemcpyDeviceToDevice, stream);

    edge_kernel<<<2048, 256, 0, stream>>>(edge_attr, edge_index, x,
                                          lin_w, lin_b, hbuf);
    mlp_kernel<<<1024, 256, 0, stream>>>(hbuf, out, w0, b0, w1, b1);
}

// Round 2
// 1421.569 us; speedup vs baseline: 1.0418x; 1.0418x over previous
//
#include <hip/hip_runtime.h>
#include <hip/hip_bf16.h>

#define NN 100000
#define NE 1600000
#define DD 64
#define HID 128

// ---------------------------------------------------------------------------
// Edge kernel: one wave per edge.
//   proj_j = lin_b[j] + sum_k edge_attr[e][k] * lin_w[j][k]
//   msg_j  = relu(x[src][j] + proj_j)
//   atomicAdd(agg[dst][j], msg_j)     (agg pre-initialized to x => h = x+agg)
// lin_w row j PINNED in 64 VGPRs of lane j (asm barrier prevents the
// compiler sinking the loads into the loop — Round 1's VGPR_Count=36 showed
// it re-fetched 16KB/edge through L1, which was the 930us bottleneck).
// edge_attr row is wave-uniform -> s_load broadcasts.
// ---------------------------------------------------------------------------
__global__ __launch_bounds__(256, 4)
void edge_kernel(const float* __restrict__ edge_attr,
                 const int*   __restrict__ edge_index,
                 const float* __restrict__ x,
                 const float* __restrict__ lin_w,
                 const float* __restrict__ lin_b,
                 float* agg)
{
    const int lane = threadIdx.x & 63;
    int wid = blockIdx.x * (blockDim.x >> 6) + (threadIdx.x >> 6);
    wid = __builtin_amdgcn_readfirstlane(wid);
    const int nwaves = gridDim.x * (blockDim.x >> 6);

    // Load lin_w row `lane` into registers (64 VGPRs) and PIN them.
    float w[DD];
    const float4* wrow = reinterpret_cast<const float4*>(lin_w + lane * DD);
    #pragma unroll
    for (int q = 0; q < DD / 4; ++q) {
        float4 v = wrow[q];
        w[4 * q + 0] = v.x; w[4 * q + 1] = v.y;
        w[4 * q + 2] = v.z; w[4 * q + 3] = v.w;
    }
    #pragma unroll
    for (int k = 0; k < DD; ++k) asm volatile("" : "+v"(w[k]));  // keep in VGPRs
    const float bj = lin_b[lane];

    for (int e = wid; e < NE; e += nwaves) {
        const int src = edge_index[e];        // wave-uniform -> s_load
        const int dst = edge_index[NE + e];   // wave-uniform -> s_load
        const float* ea = edge_attr + (size_t)e * DD;  // uniform base

        float xv = x[(size_t)src * DD + lane]; // issue gather early (vmem pipe)

        // 4 independent FMA chains (serial chain was 64x4cyc latency).
        float a0 = 0.f, a1 = 0.f, a2 = 0.f, a3 = 0.f;
        #pragma unroll
        for (int k = 0; k < DD; k += 4) {
            a0 = fmaf(ea[k + 0], w[k + 0], a0);   // s_load broadcast * VGPR
            a1 = fmaf(ea[k + 1], w[k + 1], a1);
            a2 = fmaf(ea[k + 2], w[k + 2], a2);
            a3 = fmaf(ea[k + 3], w[k + 3], a3);
        }
        float m = xv + bj + ((a0 + a1) + (a2 + a3));
        m = m > 0.0f ? m : 0.0f;
        unsafeAtomicAdd(&agg[(size_t)dst * DD + lane], m);
    }
}

// ---------------------------------------------------------------------------
// Node MLP: one wave per PAIR of nodes.
//   h1 = relu(W0 h + b0)   layer1: lane j computes rows j and j+64, h from
//                          wave-uniform scalar loads, W0 rows PINNED in
//                          128 VGPRs (same sinking fix as edge kernel).
//   out = W1 h1 + b1       layer2: W1 transposed in LDS (lane-consecutive,
//                          conflict-free b32); h1 broadcast via ds_read_b128.
// ---------------------------------------------------------------------------
__global__ __launch_bounds__(256, 2)
void mlp_kernel(const float* __restrict__ h_in,
                float* out,
                const float* __restrict__ w0, const float* __restrict__ b0,
                const float* __restrict__ w1, const float* __restrict__ b1)
{
    __shared__ float W1t[HID * DD];          // W1t[k*64 + j] = w1[j*128 + k]
    __shared__ float h1buf[4][2][HID];       // [wave][node-in-pair][k]

    for (int i = threadIdx.x; i < HID * DD; i += blockDim.x) {
        int j = i >> 7;          // w1 row (output dim, 0..63)
        int k = i & 127;         // w1 col (hidden dim, 0..127)
        W1t[k * DD + j] = w1[i]; // coalesced global read
    }
    __syncthreads();

    const int lane = threadIdx.x & 63;
    const int wv   = threadIdx.x >> 6;
    int wid = blockIdx.x * (blockDim.x >> 6) + wv;
    wid = __builtin_amdgcn_readfirstlane(wid);
    const int nwaves = gridDim.x * (blockDim.x >> 6);

    // W0 rows `lane` and `lane+64` in registers (128 VGPRs), PINNED.
    float w0a[DD], w0b[DD];
    const float4* r0 = reinterpret_cast<const float4*>(w0 + lane * DD);
    const float4* r1 = reinterpret_cast<const float4*>(w0 + (lane + 64) * DD);
    #pragma unroll
    for (int q = 0; q < DD / 4; ++q) {
        float4 va = r0[q], vb = r1[q];
        w0a[4*q+0]=va.x; w0a[4*q+1]=va.y; w0a[4*q+2]=va.z; w0a[4*q+3]=va.w;
        w0b[4*q+0]=vb.x; w0b[4*q+1]=vb.y; w0b[4*q+2]=vb.z; w0b[4*q+3]=vb.w;
    }
    #pragma unroll
    for (int k = 0; k < DD; ++k) {
        asm volatile("" : "+v"(w0a[k]));
        asm volatile("" : "+v"(w0b[k]));
    }
    const float b0a = b0[lane], b0b = b0[lane + 64];
    const float b1j = b1[lane];

    const int npairs = NN / 2;
    for (int p = wid; p < npairs; p += nwaves) {
        // ---- layer 1, two nodes sequentially (SGPR h reused) ----
        #pragma unroll
        for (int t = 0; t < 2; ++t) {
            const float* h = h_in + (size_t)(2 * p + t) * DD;  // uniform
            float a0 = b0a, a1 = b0b, c0 = 0.f, c1 = 0.f;
            #pragma unroll
            for (int k = 0; k < DD; k += 2) {
                float hk0 = h[k], hk1 = h[k + 1];   // s_load broadcast
                a0 = fmaf(hk0, w0a[k], a0);
                a1 = fmaf(hk0, w0b[k], a1);
                c0 = fmaf(hk1, w0a[k + 1], c0);
                c1 = fmaf(hk1, w0b[k + 1], c1);
            }
            a0 += c0; a1 += c1;
            a0 = a0 > 0.0f ? a0 : 0.0f;
            a1 = a1 > 0.0f ? a1 : 0.0f;
            h1buf[wv][t][lane]      = a0;
            h1buf[wv][t][lane + 64] = a1;
        }
        // wave-synchronous LDS (same wave wrote it; compiler inserts waitcnt)

        // ---- layer 2, both nodes share the W1t reads ----
        const float4* h0v = reinterpret_cast<const float4*>(&h1buf[wv][0][0]);
        const float4* h1v = reinterpret_cast<const float4*>(&h1buf[wv][1][0]);
        float acc0 = b1j, acc1 = b1j;
        #pragma unroll
        for (int k4 = 0; k4 < HID / 4; ++k4) {
            float4 p0 = h0v[k4];                  // ds_read_b128 broadcast
            float4 p1 = h1v[k4];
            int kb = 4 * k4;
            float wk0 = W1t[(kb + 0) * DD + lane];  // conflict-free ds_read
            float wk1 = W1t[(kb + 1) * DD + lane];
            float wk2 = W1t[(kb + 2) * DD + lane];
            float wk3 = W1t[(kb + 3) * DD + lane];
            acc0 = fmaf(p0.x, wk0, acc0); acc1 = fmaf(p1.x, wk0, acc1);
            acc0 = fmaf(p0.y, wk1, acc0); acc1 = fmaf(p1.y, wk1, acc1);
            acc0 = fmaf(p0.z, wk2, acc0); acc1 = fmaf(p1.z, wk2, acc1);
            acc0 = fmaf(p0.w, wk3, acc0); acc1 = fmaf(p1.w, wk3, acc1);
        }
        out[(size_t)(2 * p + 0) * DD + lane] = acc0;
        out[(size_t)(2 * p + 1) * DD + lane] = acc1;
    }
}

extern "C" void kernel_launch(void* const* d_in, const int* in_sizes, int n_in,
                              void* d_out, int out_size, void* d_ws, size_t ws_size,
                              hipStream_t stream) {
    const float* x         = (const float*)d_in[0];
    const int*   edge_index= (const int*)  d_in[1];
    const float* edge_attr = (const float*)d_in[2];
    const float* lin_w     = (const float*)d_in[3];
    const float* lin_b     = (const float*)d_in[4];
    const float* w0        = (const float*)d_in[5];
    const float* b0        = (const float*)d_in[6];
    const float* w1        = (const float*)d_in[7];
    const float* b1        = (const float*)d_in[8];
    float* out = (float*)d_out;

    const size_t hbytes = (size_t)NN * DD * sizeof(float);
    float* hbuf = (ws_size >= hbytes) ? (float*)d_ws : out;

    // h starts as x (EPS=0: h = (1+eps)*x + agg).
    hipMemcpyAsync(hbuf, x, hbytes, hipMemcpyDeviceToDevice, stream);

    edge_kernel<<<2048, 256, 0, stream>>>(edge_attr, edge_index, x,
                                          lin_w, lin_b, hbuf);
    mlp_kernel<<<1024, 256, 0, stream>>>(hbuf, out, w0, b0, w1, b1);
}